// Round 7
// baseline (506.544 us; speedup 1.0000x reference)
//
#include <hip/hip_runtime.h>
#include <hip/hip_bf16.h>

#define B_ 64
#define S_ 4096
#define H_ 512
#define E_ 512
#define NEG_INF_ -1e10f

typedef __attribute__((ext_vector_type(8))) short short8;
typedef __attribute__((ext_vector_type(16))) float f32x16;

static __device__ __forceinline__ unsigned short f2bf(float f) {
    union { float f; unsigned u; } v; v.f = f;
    unsigned x = v.u;
    x += 0x7FFFu + ((x >> 16) & 1u);   // round-to-nearest-even
    return (unsigned short)(x >> 16);
}

// vendor RNE pair conversion (verified r3/r5/r6: absmax 4.9e-4)
static __device__ __forceinline__ unsigned pk2(float lo, float hi) {
    float2 f; f.x = lo; f.y = hi;
    union { __hip_bfloat162 h; unsigned u; } c;
    c.h = __float22bfloat162_rn(f);
    return c.u;
}

static __device__ __forceinline__ void gload_lds16(const void* g, void* l) {
    __builtin_amdgcn_global_load_lds(
        (const __attribute__((address_space(1))) void*)g,
        (__attribute__((address_space(3))) void*)l, 16, 0, 0);
}

#define VMCNT6 do { asm volatile("s_waitcnt vmcnt(6)" ::: "memory"); __builtin_amdgcn_sched_barrier(0); } while (0)
#define VMCNT0 do { asm volatile("s_waitcnt vmcnt(0)" ::: "memory"); __builtin_amdgcn_sched_barrier(0); } while (0)
#define LGKM0  do { asm volatile("s_waitcnt lgkmcnt(0)" ::: "memory"); __builtin_amdgcn_sched_barrier(0); } while (0)

// ---------------- prep: Wkt[h][e] = bf16(Wk[e][h]) ----------------
__global__ void prep_wkt(const float* __restrict__ wk, unsigned short* __restrict__ wkt) {
    int idx = blockIdx.x * 256 + threadIdx.x;
    int h = idx >> 9, e = idx & 511;
    wkt[idx] = f2bf(wk[e * H_ + h]);
}

// ---------------- prep: qb[b][h] = hidden[b]@Wq[:,h] + bq[h] + bk[h] ----------------
__global__ void prep_qb(const float* __restrict__ hidden, const float* __restrict__ wq,
                        const float* __restrict__ bq, const float* __restrict__ bk,
                        float* __restrict__ qb) {
    __shared__ float hid[H_];
    int b = blockIdx.x, t = threadIdx.x;           // 256 threads
    hid[t]       = hidden[b * H_ + t];
    hid[t + 256] = hidden[b * H_ + t + 256];
    __syncthreads();
    for (int hh = t; hh < H_; hh += 256) {
        float s = 0.f;
        for (int e = 0; e < H_; ++e) s += hid[e] * wq[e * H_ + hh];
        qb[b * H_ + hh] = s + bq[hh] + bk[hh];
    }
}

// ---------------- main: partial scores over one 128-col n-chunk ----------------
// grid 8192: xcd-chunked -> (b, s-tile 128, n-tile 128). block 256 thr = 4 waves (2M x 2N).
// A (enc f32) -> regs -> cvt bf16 -> ds_write (2-buf ping-pong, ROTATION layout sst=(sl+srow)&15).
// B (Wkt bf16) -> global_load_lds DMA (3-buf ring, XOR layout, source-permuted) [r5/r6: 0-conflict].
// Fully-unrolled kc loop, counted vmcnt(6), raw s_barrier (one per kc), depth-2 prefetch.
__global__ __launch_bounds__(256, 4) void scores_kernel(
    const float* __restrict__ enc, const unsigned short* __restrict__ wkt,
    const float* __restrict__ qb, const float* __restrict__ wv,
    float* __restrict__ part)
{
    __shared__ char lds[40960];   // A0@0, A1@8K, B0@16K, B1@24K, B2@32K

    int id = blockIdx.x;
    int xcd = id & 7, qq = id >> 3;
    int logical = xcd * 1024 + qq;
    int b  = logical >> 7;
    int r  = logical & 127;
    int st = r >> 2, nt = r & 3;
    int s0 = st * 128;

    const int tid  = threadIdx.x;
    const int lane = tid & 63;
    const int wave = tid >> 6;
    const int wr   = wave >> 1;      // M half (0,1)
    const int wc   = wave & 1;       // N half (0,1)
    const int l31  = lane & 31;
    const int g    = lane >> 5;

    const float* encb = enc + ((size_t)b * S_ + s0) * E_;

    // ---- A mapping: thread t, j in {0,1}: row = t&127, ksl = (t>>7)*2 + j ----
    const int arow   = tid & 127;
    const int aksl0  = (tid >> 7) * 2;
    const float* aptr = encb + (size_t)arow * 512 + aksl0 * 8;   // + kc*32 (+8 for j=1)
    const int asrow  = arow & 31;
    const int aslb   = (arow >> 5) * 4 + aksl0;                  // logical slot base
    char* const awb0 = (char*)0 + asrow * 256 + (((aslb + 0 + asrow) & 15) << 4);
    char* const awb1 = (char*)0 + asrow * 256 + (((aslb + 1 + asrow) & 15) << 4);

    auto loadA = [&](int kc, float4 (&st_)[4]) {
        const float* p = aptr + kc * 32;
        st_[0] = *(const float4*)(p);
        st_[1] = *(const float4*)(p + 4);
        st_[2] = *(const float4*)(p + 8);
        st_[3] = *(const float4*)(p + 12);
    };
    auto writeA = [&](char* buf, const float4 (&st_)[4]) {
        union { short8 s; unsigned u[4]; } u0, u1;
        u0.u[0] = pk2(st_[0].x, st_[0].y); u0.u[1] = pk2(st_[0].z, st_[0].w);
        u0.u[2] = pk2(st_[1].x, st_[1].y); u0.u[3] = pk2(st_[1].z, st_[1].w);
        u1.u[0] = pk2(st_[2].x, st_[2].y); u1.u[1] = pk2(st_[2].z, st_[2].w);
        u1.u[2] = pk2(st_[3].x, st_[3].y); u1.u[3] = pk2(st_[3].z, st_[3].w);
        *(short8*)(buf + (size_t)awb0) = u0.s;
        *(short8*)(buf + (size_t)awb1) = u1.s;
    };
    // ---- B: 128 n x 32 k bf16 = 8KB DMA; stored [sn 32][16]: sl = ss^(sn&15); n=(sl>>2)*32+sn; k=(sl&3)*8
    auto stageB = [&](int kc, char* buf) {
#pragma unroll
        for (int p = 0; p < 2; ++p) {
            int gi0 = p * 256 + wave * 64;
            char* db = buf + gi0 * 16;                 // wave-uniform dest
            int gi = gi0 + lane;
            int sn = gi >> 4, ss = gi & 15;
            int sl = ss ^ (sn & 15);
            int n  = (sl >> 2) * 32 + sn;
            const unsigned short* gp = wkt + (size_t)(nt * 128 + n) * 512 + kc * 32 + (sl & 3) * 8;
            gload_lds16(gp, db);
        }
    };

    f32x16 acc[2][2];
#pragma unroll
    for (int mr = 0; mr < 2; ++mr)
#pragma unroll
        for (int nf = 0; nf < 2; ++nf)
#pragma unroll
            for (int e = 0; e < 16; ++e) acc[mr][nf][e] = 0.f;

    float4 ra[4], rb[4];

    // prologue: FIFO = [B0(2), A0(4)], [B1(2), A1(4)]
    stageB(0, lds + 16384);          loadA(0, ra);
    stageB(1, lds + 16384 + 8192);   loadA(1, rb);

#pragma unroll
    for (int kc = 0; kc < 16; ++kc) {
        if (kc < 15) { VMCNT6; } else { VMCNT0; }       // B(kc)+A(kc) retired
        char* Ab = lds + (kc & 1) * 8192;
        if (kc & 1) writeA(Ab, rb); else writeA(Ab, ra);
        LGKM0;
        __builtin_amdgcn_s_barrier();
        __builtin_amdgcn_sched_barrier(0);
        if (kc < 14) {                                   // issue stage kc+2: [B, A]
            stageB(kc + 2, lds + 16384 + ((kc + 2) % 3) * 8192);
            if (kc & 1) loadA(kc + 2, rb); else loadA(kc + 2, ra);
        }
        const char* Bb = lds + 16384 + (kc % 3) * 8192;
        __builtin_amdgcn_s_setprio(1);
#pragma unroll
        for (int ks = 0; ks < 2; ++ks) {
            short8 af[2], bf[2];
#pragma unroll
            for (int mr = 0; mr < 2; ++mr) {
                int sl = (wr * 2 + mr) * 4 + ks * 2 + g;
                af[mr] = *(const short8*)(Ab + l31 * 256 + (((sl + l31) & 15) << 4));
            }
#pragma unroll
            for (int nf = 0; nf < 2; ++nf) {
                int sl = (wc * 2 + nf) * 4 + ks * 2 + g;
                bf[nf] = *(const short8*)(Bb + l31 * 256 + ((sl ^ (l31 & 15)) << 4));
            }
            acc[0][0] = __builtin_amdgcn_mfma_f32_32x32x16_bf16(af[0], bf[0], acc[0][0], 0, 0, 0);
            acc[0][1] = __builtin_amdgcn_mfma_f32_32x32x16_bf16(af[0], bf[1], acc[0][1], 0, 0, 0);
            acc[1][0] = __builtin_amdgcn_mfma_f32_32x32x16_bf16(af[1], bf[0], acc[1][0], 0, 0, 0);
            acc[1][1] = __builtin_amdgcn_mfma_f32_32x32x16_bf16(af[1], bf[1], acc[1][1], 0, 0, 0);
        }
        __builtin_amdgcn_s_setprio(0);
    }

    // ---- epilogue: p = sum_nf Wv[col]*tanh(qb[col]+acc) ----
    float p[2][16];
#pragma unroll
    for (int nf = 0; nf < 2; ++nf) {
        int col = nt * 128 + wc * 64 + nf * 32 + l31;
        float qv  = qb[b * H_ + col];
        float wvv = wv[col];
#pragma unroll
        for (int mr = 0; mr < 2; ++mr)
#pragma unroll
            for (int e = 0; e < 16; ++e) {
                float x  = qv + acc[mr][nf][e];
                float ex = __expf(2.f * x);
                float th = 1.f - 2.f / (ex + 1.f);
                float v  = wvv * th;
                p[mr][e] = nf ? (p[mr][e] + v) : v;
            }
    }

    __syncthreads();                                  // all GEMM LDS traffic done before reuse
    // ---- reduce over 32 lanes via LDS transpose (stride 36 floats; r3-verified) ----
    float* ps = (float*)lds;                          // [wave][64 rows][36]
#pragma unroll
    for (int mr = 0; mr < 2; ++mr)
#pragma unroll
        for (int e = 0; e < 16; ++e) {
            int row = mr * 32 + (e & 3) + 8 * (e >> 2) + 4 * g;
            ps[(wave * 64 + row) * 36 + l31] = p[mr][e];
        }
    __syncthreads();
    float rsum = 0.f;
    {
        const float* myrow = ps + (size_t)(wave * 64 + lane) * 36;
#pragma unroll
        for (int j = 0; j < 8; ++j) {
            float4 v = *(const float4*)(myrow + j * 4);
            rsum += (v.x + v.y) + (v.z + v.w);
        }
    }
    float* pf = (float*)(lds + 36864);                // 256 floats
    pf[wave * 64 + lane] = rsum;
    __syncthreads();
    if (tid < 128) {
        int wr2 = tid >> 6, rr = tid & 63;
        float v = pf[(wr2 * 2 + 0) * 64 + rr] + pf[(wr2 * 2 + 1) * 64 + rr];
        int s = s0 + wr2 * 64 + rr;
        part[((size_t)b * S_ + s) * 4 + nt] = v;
    }
}

// ---------------- masked softmax over S per batch row (sums 4 partials) ----------------
__global__ void softmax_kernel(const float* __restrict__ part, const int* __restrict__ mask,
                               const float* __restrict__ bvp, float* __restrict__ attn) {
    __shared__ float red[8];
    int b = blockIdx.x, tid = threadIdx.x;         // 512 threads, 8 waves
    int wid = tid >> 6, lane = tid & 63;
    float bv0 = bvp[0];
    float vals[8];
    float mx = -3.4e38f;
#pragma unroll
    for (int i = 0; i < 8; ++i) {
        int s = i * 512 + tid;
        float4 v = *(const float4*)(part + ((size_t)b * S_ + s) * 4);
        float sc = (v.x + v.y) + (v.z + v.w) + bv0;
        sc = mask[(size_t)b * S_ + s] ? sc : NEG_INF_;
        vals[i] = sc;
        mx = fmaxf(mx, sc);
    }
#pragma unroll
    for (int off = 1; off < 64; off <<= 1) mx = fmaxf(mx, __shfl_xor(mx, off));
    if (lane == 0) red[wid] = mx;
    __syncthreads();
    mx = red[0];
#pragma unroll
    for (int w = 1; w < 8; ++w) mx = fmaxf(mx, red[w]);
    __syncthreads();
    float sum = 0.f;
#pragma unroll
    for (int i = 0; i < 8; ++i) { vals[i] = __expf(vals[i] - mx); sum += vals[i]; }
#pragma unroll
    for (int off = 1; off < 64; off <<= 1) sum += __shfl_xor(sum, off);
    if (lane == 0) red[wid] = sum;
    __syncthreads();
    sum = red[0] + red[1] + red[2] + red[3] + red[4] + red[5] + red[6] + red[7];
    float inv = 1.f / sum;
#pragma unroll
    for (int i = 0; i < 8; ++i) attn[(size_t)b * S_ + i * 512 + tid] = vals[i] * inv;
}

// ---------------- context partial sums: part[c][b][e] ----------------
__global__ void ctx_partial(const float* __restrict__ attn, const float* __restrict__ enc,
                            float* __restrict__ part) {
    __shared__ float a[256];
    int c = blockIdx.x, b = blockIdx.y, t = threadIdx.x;   // 256 threads
    a[t] = attn[(size_t)b * S_ + c * 256 + t];
    __syncthreads();
    const float* ep = enc + (size_t)b * S_ * E_ + (size_t)c * 256 * E_ + t * 2;
    float x = 0.f, y = 0.f;
#pragma unroll 4
    for (int s = 0; s < 256; ++s) {
        float2 v = *(const float2*)(ep + (size_t)s * E_);
        x += a[s] * v.x;
        y += a[s] * v.y;
    }
    float* o = part + ((size_t)c * B_ + b) * E_ + t * 2;
    o[0] = x; o[1] = y;
}

__global__ void ctx_reduce(const float* __restrict__ part, float* __restrict__ ctx) {
    int idx = blockIdx.x * 256 + threadIdx.x;       // 0..32767
    float s = 0.f;
#pragma unroll
    for (int c = 0; c < 16; ++c) s += part[(size_t)c * (B_ * E_) + idx];
    ctx[idx] = s;
}

extern "C" void kernel_launch(void* const* d_in, const int* in_sizes, int n_in,
                              void* d_out, int out_size, void* d_ws, size_t ws_size,
                              hipStream_t stream) {
    const float* hidden = (const float*)d_in[0];
    const float* enc    = (const float*)d_in[1];
    const int*   mask   = (const int*)d_in[2];
    const float* Wq     = (const float*)d_in[3];
    const float* bq     = (const float*)d_in[4];
    const float* Wk     = (const float*)d_in[5];
    const float* bk     = (const float*)d_in[6];
    const float* Wv     = (const float*)d_in[7];
    const float* bv     = (const float*)d_in[8];

    float* out  = (float*)d_out;               // [B*E context][B*S attn]
    char*  ws   = (char*)d_ws;
    float*          qbuf   = (float*)ws;                         // 131072 B
    unsigned short* wkt    = (unsigned short*)(ws + 131072);     // 524288 B
    float*          pscore = (float*)(ws + 655360);              // 4 MB [b][s][4]
    float*          cpart  = (float*)(ws + 655360);              // aliases pscore (after softmax)

    float* ctx  = out;
    float* attn = out + B_ * E_;

    prep_wkt<<<1024, 256, 0, stream>>>(Wk, wkt);
    prep_qb<<<64, 256, 0, stream>>>(hidden, Wq, bq, bk, qbuf);
    scores_kernel<<<8192, 256, 0, stream>>>(enc, wkt, qbuf, Wv, pscore);
    softmax_kernel<<<64, 512, 0, stream>>>(pscore, mask, bv, attn);
    ctx_partial<<<dim3(16, 64), 256, 0, stream>>>(attn, enc, cpart);
    ctx_reduce<<<128, 256, 0, stream>>>(cpart, ctx);
}

// Round 8
// 498.044 us; speedup vs baseline: 1.0171x; 1.0171x over previous
//
#include <hip/hip_runtime.h>
#include <hip/hip_bf16.h>

#define B_ 64
#define S_ 4096
#define H_ 512
#define E_ 512
#define NEG_INF_ -1e10f

typedef __attribute__((ext_vector_type(8))) short short8;
typedef __attribute__((ext_vector_type(16))) float f32x16;

static __device__ __forceinline__ unsigned short f2bf(float f) {
    union { float f; unsigned u; } v; v.f = f;
    unsigned x = v.u;
    x += 0x7FFFu + ((x >> 16) & 1u);   // round-to-nearest-even
    return (unsigned short)(x >> 16);
}

// vendor RNE pair conversion (verified r3/r5/r6/r7: absmax 4.9e-4)
static __device__ __forceinline__ unsigned pk2(float lo, float hi) {
    float2 f; f.x = lo; f.y = hi;
    union { __hip_bfloat162 h; unsigned u; } c;
    c.h = __float22bfloat162_rn(f);
    return c.u;
}

static __device__ __forceinline__ void gload_lds16(const void* g, void* l) {
    __builtin_amdgcn_global_load_lds(
        (const __attribute__((address_space(1))) void*)g,
        (__attribute__((address_space(3))) void*)l, 16, 0, 0);
}

#define VMCNT6 do { asm volatile("s_waitcnt vmcnt(6)" ::: "memory"); __builtin_amdgcn_sched_barrier(0); } while (0)
#define VMCNT0 do { asm volatile("s_waitcnt vmcnt(0)" ::: "memory"); __builtin_amdgcn_sched_barrier(0); } while (0)
#define LGKM0  do { asm volatile("s_waitcnt lgkmcnt(0)" ::: "memory"); __builtin_amdgcn_sched_barrier(0); } while (0)

// ---------------- prep: Wkt[h][e] = bf16(Wk[e][h]) ----------------
__global__ void prep_wkt(const float* __restrict__ wk, unsigned short* __restrict__ wkt) {
    int idx = blockIdx.x * 256 + threadIdx.x;
    int h = idx >> 9, e = idx & 511;
    wkt[idx] = f2bf(wk[e * H_ + h]);
}

// ---------------- prep: qb[b][h] = hidden[b]@Wq[:,h] + bq[h] + bk[h] ----------------
__global__ void prep_qb(const float* __restrict__ hidden, const float* __restrict__ wq,
                        const float* __restrict__ bq, const float* __restrict__ bk,
                        float* __restrict__ qb) {
    __shared__ float hid[H_];
    int b = blockIdx.x, t = threadIdx.x;           // 256 threads
    hid[t]       = hidden[b * H_ + t];
    hid[t + 256] = hidden[b * H_ + t + 256];
    __syncthreads();
    for (int hh = t; hh < H_; hh += 256) {
        float s = 0.f;
        for (int e = 0; e < H_; ++e) s += hid[e] * wq[e * H_ + hh];
        qb[b * H_ + hh] = s + bq[hh] + bk[hh];
    }
}

// ---------------- main: partial scores over one 128-col n-chunk ----------------
// grid 8192: xcd-chunked -> (b, s-tile 128, n-tile 128). block 256 thr = 4 waves (2M x 2N).
// A (enc f32): COALESCED loads (8 lanes/row, 128B contiguous per row, 16 full lines/instr)
//   -> regs -> cvt bf16 -> 4x ds_write_b64 (2-buf ping-pong, ROTATION layout (sl+srow)&15
//   [r7-verified 0-conflict on reads; write bank-math hits 4-cyc minimum]).
// B (Wkt bf16) -> global_load_lds DMA (3-buf ring, XOR layout, source-permuted) [r5-r7: 0-conflict].
// Fully-unrolled kc loop, counted vmcnt(6), raw s_barrier (one per kc), depth-2 prefetch.
// r6 regime: launch_bounds(256,3), NO setprio (r7: bounds-4 + setprio regressed).
__global__ __launch_bounds__(256, 3) void scores_kernel(
    const float* __restrict__ enc, const unsigned short* __restrict__ wkt,
    const float* __restrict__ qb, const float* __restrict__ wv,
    float* __restrict__ part)
{
    __shared__ char lds[40960];   // A0@0, A1@8K, B0@16K, B1@24K, B2@32K

    int id = blockIdx.x;
    int xcd = id & 7, qq = id >> 3;
    int logical = xcd * 1024 + qq;
    int b  = logical >> 7;
    int r  = logical & 127;
    int st = r >> 2, nt = r & 3;
    int s0 = st * 128;

    const int tid  = threadIdx.x;
    const int lane = tid & 63;
    const int wave = tid >> 6;
    const int wr   = wave >> 1;      // M half (0,1)
    const int wc   = wave & 1;       // N half (0,1)
    const int l31  = lane & 31;
    const int g    = lane >> 5;

    const float* encb = enc + ((size_t)b * S_ + s0) * E_;

    // ---- A mapping (coalesced): instr j: row = j*32 + (tid>>3), floats (tid&7)*4 .. +3.
    //      Per 64-lane instr: 8 rows x 128B contiguous.
    const int srow = tid >> 3;                     // 0..31 (= row & 31 for all j)
    const int fl   = tid & 7;                      // 16B chunk index within 128B row-chunk
    const float* aptr = encb + (size_t)srow * 512 + fl * 4;   // + j*16384 + kc*32

    auto loadA = [&](int kc, float4 (&st_)[4]) {
#pragma unroll
        for (int j = 0; j < 4; ++j)
            st_[j] = *(const float4*)(aptr + j * 16384 + kc * 32);
    };
    // writeA: chunk (row=j*32+srow, k=fl*4): slot sl=j*4+(fl>>1), rotated sst=(sl+srow)&15,
    // byte = srow*256 + sst*16 + (fl&1)*8   (ds_write_b64 per j)
    auto writeA = [&](char* buf, const float4 (&st_)[4]) {
#pragma unroll
        for (int j = 0; j < 4; ++j) {
            int sst = ((j * 4 + (fl >> 1)) + srow) & 15;
            uint2 w;
            w.x = pk2(st_[j].x, st_[j].y);
            w.y = pk2(st_[j].z, st_[j].w);
            *(uint2*)(buf + srow * 256 + sst * 16 + (fl & 1) * 8) = w;
        }
    };
    // ---- B: 128 n x 32 k bf16 = 8KB DMA; stored [sn 32][16]: sl = ss^(sn&15); n=(sl>>2)*32+sn; k=(sl&3)*8
    auto stageB = [&](int kc, char* buf) {
#pragma unroll
        for (int p = 0; p < 2; ++p) {
            int gi0 = p * 256 + wave * 64;
            char* db = buf + gi0 * 16;                 // wave-uniform dest
            int gi = gi0 + lane;
            int sn = gi >> 4, ss = gi & 15;
            int sl = ss ^ (sn & 15);
            int n  = (sl >> 2) * 32 + sn;
            const unsigned short* gp = wkt + (size_t)(nt * 128 + n) * 512 + kc * 32 + (sl & 3) * 8;
            gload_lds16(gp, db);
        }
    };

    f32x16 acc[2][2];
#pragma unroll
    for (int mr = 0; mr < 2; ++mr)
#pragma unroll
        for (int nf = 0; nf < 2; ++nf)
#pragma unroll
            for (int e = 0; e < 16; ++e) acc[mr][nf][e] = 0.f;

    float4 ra[4], rb[4];

    // prologue: FIFO = [B0(2), A0(4)], [B1(2), A1(4)]  -> 12 vm ops in flight
    stageB(0, lds + 16384);          loadA(0, ra);
    stageB(1, lds + 16384 + 8192);   loadA(1, rb);

#pragma unroll
    for (int kc = 0; kc < 16; ++kc) {
        if (kc < 15) { VMCNT6; } else { VMCNT0; }       // B(kc)+A(kc) retired
        char* Ab = lds + (kc & 1) * 8192;
        if (kc & 1) writeA(Ab, rb); else writeA(Ab, ra);
        LGKM0;
        __builtin_amdgcn_s_barrier();
        __builtin_amdgcn_sched_barrier(0);
        if (kc < 14) {                                   // issue stage kc+2: [B, A]
            stageB(kc + 2, lds + 16384 + ((kc + 2) % 3) * 8192);
            if (kc & 1) loadA(kc + 2, rb); else loadA(kc + 2, ra);
        }
        const char* Bb = lds + 16384 + (kc % 3) * 8192;
#pragma unroll
        for (int ks = 0; ks < 2; ++ks) {
            short8 af[2], bf[2];
#pragma unroll
            for (int mr = 0; mr < 2; ++mr) {
                int sl = (wr * 2 + mr) * 4 + ks * 2 + g;
                af[mr] = *(const short8*)(Ab + l31 * 256 + (((sl + l31) & 15) << 4));
            }
#pragma unroll
            for (int nf = 0; nf < 2; ++nf) {
                int sl = (wc * 2 + nf) * 4 + ks * 2 + g;
                bf[nf] = *(const short8*)(Bb + l31 * 256 + ((sl ^ (l31 & 15)) << 4));
            }
            acc[0][0] = __builtin_amdgcn_mfma_f32_32x32x16_bf16(af[0], bf[0], acc[0][0], 0, 0, 0);
            acc[0][1] = __builtin_amdgcn_mfma_f32_32x32x16_bf16(af[0], bf[1], acc[0][1], 0, 0, 0);
            acc[1][0] = __builtin_amdgcn_mfma_f32_32x32x16_bf16(af[1], bf[0], acc[1][0], 0, 0, 0);
            acc[1][1] = __builtin_amdgcn_mfma_f32_32x32x16_bf16(af[1], bf[1], acc[1][1], 0, 0, 0);
        }
    }

    // ---- epilogue: p = sum_nf Wv[col]*tanh(qb[col]+acc) ----
    float p[2][16];
#pragma unroll
    for (int nf = 0; nf < 2; ++nf) {
        int col = nt * 128 + wc * 64 + nf * 32 + l31;
        float qv  = qb[b * H_ + col];
        float wvv = wv[col];
#pragma unroll
        for (int mr = 0; mr < 2; ++mr)
#pragma unroll
            for (int e = 0; e < 16; ++e) {
                float x  = qv + acc[mr][nf][e];
                float ex = __expf(2.f * x);
                float th = 1.f - 2.f / (ex + 1.f);
                float v  = wvv * th;
                p[mr][e] = nf ? (p[mr][e] + v) : v;
            }
    }

    __syncthreads();                                  // all GEMM LDS traffic done before reuse
    // ---- reduce over 32 lanes via LDS transpose (stride 36 floats; r3-verified) ----
    float* ps = (float*)lds;                          // [wave][64 rows][36]
#pragma unroll
    for (int mr = 0; mr < 2; ++mr)
#pragma unroll
        for (int e = 0; e < 16; ++e) {
            int row = mr * 32 + (e & 3) + 8 * (e >> 2) + 4 * g;
            ps[(wave * 64 + row) * 36 + l31] = p[mr][e];
        }
    __syncthreads();
    float rsum = 0.f;
    {
        const float* myrow = ps + (size_t)(wave * 64 + lane) * 36;
#pragma unroll
        for (int j = 0; j < 8; ++j) {
            float4 v = *(const float4*)(myrow + j * 4);
            rsum += (v.x + v.y) + (v.z + v.w);
        }
    }
    float* pf = (float*)(lds + 36864);                // 256 floats
    pf[wave * 64 + lane] = rsum;
    __syncthreads();
    if (tid < 128) {
        int wr2 = tid >> 6, rr = tid & 63;
        float v = pf[(wr2 * 2 + 0) * 64 + rr] + pf[(wr2 * 2 + 1) * 64 + rr];
        int s = s0 + wr2 * 64 + rr;
        part[((size_t)b * S_ + s) * 4 + nt] = v;
    }
}

// ---------------- masked softmax over S per batch row (sums 4 partials) ----------------
__global__ void softmax_kernel(const float* __restrict__ part, const int* __restrict__ mask,
                               const float* __restrict__ bvp, float* __restrict__ attn) {
    __shared__ float red[8];
    int b = blockIdx.x, tid = threadIdx.x;         // 512 threads, 8 waves
    int wid = tid >> 6, lane = tid & 63;
    float bv0 = bvp[0];
    float vals[8];
    float mx = -3.4e38f;
#pragma unroll
    for (int i = 0; i < 8; ++i) {
        int s = i * 512 + tid;
        float4 v = *(const float4*)(part + ((size_t)b * S_ + s) * 4);
        float sc = (v.x + v.y) + (v.z + v.w) + bv0;
        sc = mask[(size_t)b * S_ + s] ? sc : NEG_INF_;
        vals[i] = sc;
        mx = fmaxf(mx, sc);
    }
#pragma unroll
    for (int off = 1; off < 64; off <<= 1) mx = fmaxf(mx, __shfl_xor(mx, off));
    if (lane == 0) red[wid] = mx;
    __syncthreads();
    mx = red[0];
#pragma unroll
    for (int w = 1; w < 8; ++w) mx = fmaxf(mx, red[w]);
    __syncthreads();
    float sum = 0.f;
#pragma unroll
    for (int i = 0; i < 8; ++i) { vals[i] = __expf(vals[i] - mx); sum += vals[i]; }
#pragma unroll
    for (int off = 1; off < 64; off <<= 1) sum += __shfl_xor(sum, off);
    if (lane == 0) red[wid] = sum;
    __syncthreads();
    sum = red[0] + red[1] + red[2] + red[3] + red[4] + red[5] + red[6] + red[7];
    float inv = 1.f / sum;
#pragma unroll
    for (int i = 0; i < 8; ++i) attn[(size_t)b * S_ + i * 512 + tid] = vals[i] * inv;
}

// ---------------- context partial sums: part[c][b][e] ----------------
__global__ void ctx_partial(const float* __restrict__ attn, const float* __restrict__ enc,
                            float* __restrict__ part) {
    __shared__ float a[256];
    int c = blockIdx.x, b = blockIdx.y, t = threadIdx.x;   // 256 threads
    a[t] = attn[(size_t)b * S_ + c * 256 + t];
    __syncthreads();
    const float* ep = enc + (size_t)b * S_ * E_ + (size_t)c * 256 * E_ + t * 2;
    float x = 0.f, y = 0.f;
#pragma unroll 4
    for (int s = 0; s < 256; ++s) {
        float2 v = *(const float2*)(ep + (size_t)s * E_);
        x += a[s] * v.x;
        y += a[s] * v.y;
    }
    float* o = part + ((size_t)c * B_ + b) * E_ + t * 2;
    o[0] = x; o[1] = y;
}

__global__ void ctx_reduce(const float* __restrict__ part, float* __restrict__ ctx) {
    int idx = blockIdx.x * 256 + threadIdx.x;       // 0..32767
    float s = 0.f;
#pragma unroll
    for (int c = 0; c < 16; ++c) s += part[(size_t)c * (B_ * E_) + idx];
    ctx[idx] = s;
}

extern "C" void kernel_launch(void* const* d_in, const int* in_sizes, int n_in,
                              void* d_out, int out_size, void* d_ws, size_t ws_size,
                              hipStream_t stream) {
    const float* hidden = (const float*)d_in[0];
    const float* enc    = (const float*)d_in[1];
    const int*   mask   = (const int*)d_in[2];
    const float* Wq     = (const float*)d_in[3];
    const float* bq     = (const float*)d_in[4];
    const float* Wk     = (const float*)d_in[5];
    const float* bk     = (const float*)d_in[6];
    const float* Wv     = (const float*)d_in[7];
    const float* bv     = (const float*)d_in[8];

    float* out  = (float*)d_out;               // [B*E context][B*S attn]
    char*  ws   = (char*)d_ws;
    float*          qbuf   = (float*)ws;                         // 131072 B
    unsigned short* wkt    = (unsigned short*)(ws + 131072);     // 524288 B
    float*          pscore = (float*)(ws + 655360);              // 4 MB [b][s][4]
    float*          cpart  = (float*)(ws + 655360);              // aliases pscore (after softmax)

    float* ctx  = out;
    float* attn = out + B_ * E_;

    prep_wkt<<<1024, 256, 0, stream>>>(Wk, wkt);
    prep_qb<<<64, 256, 0, stream>>>(hidden, Wq, bq, bk, qbuf);
    scores_kernel<<<8192, 256, 0, stream>>>(enc, wkt, qbuf, Wv, pscore);
    softmax_kernel<<<64, 512, 0, stream>>>(pscore, mask, bv, attn);
    ctx_partial<<<dim3(16, 64), 256, 0, stream>>>(attn, enc, cpart);
    ctx_reduce<<<128, 256, 0, stream>>>(cpart, ctx);
}

// Round 9
// 434.351 us; speedup vs baseline: 1.1662x; 1.1466x over previous
//
#include <hip/hip_runtime.h>
#include <hip/hip_bf16.h>

#define B_ 64
#define S_ 4096
#define H_ 512
#define E_ 512
#define NEG_INF_ -1e10f

typedef __attribute__((ext_vector_type(8))) short short8;
typedef __attribute__((ext_vector_type(16))) float f32x16;

static __device__ __forceinline__ unsigned short f2bf(float f) {
    union { float f; unsigned u; } v; v.f = f;
    unsigned x = v.u;
    x += 0x7FFFu + ((x >> 16) & 1u);   // round-to-nearest-even
    return (unsigned short)(x >> 16);
}

// vendor RNE pair conversion (verified r3/r5-r8: absmax 4.9e-4)
static __device__ __forceinline__ unsigned pk2(float lo, float hi) {
    float2 f; f.x = lo; f.y = hi;
    union { __hip_bfloat162 h; unsigned u; } c;
    c.h = __float22bfloat162_rn(f);
    return c.u;
}

static __device__ __forceinline__ void gload_lds16(const void* g, void* l) {
    __builtin_amdgcn_global_load_lds(
        (const __attribute__((address_space(1))) void*)g,
        (__attribute__((address_space(3))) void*)l, 16, 0, 0);
}

#define VMCNT12 do { asm volatile("s_waitcnt vmcnt(12)" ::: "memory"); __builtin_amdgcn_sched_barrier(0); } while (0)
#define VMCNT6  do { asm volatile("s_waitcnt vmcnt(6)"  ::: "memory"); __builtin_amdgcn_sched_barrier(0); } while (0)
#define VMCNT0  do { asm volatile("s_waitcnt vmcnt(0)"  ::: "memory"); __builtin_amdgcn_sched_barrier(0); } while (0)
#define LGKM0   do { asm volatile("s_waitcnt lgkmcnt(0)" ::: "memory"); __builtin_amdgcn_sched_barrier(0); } while (0)

// ---------------- prep: Wkt[h][e] = bf16(Wk[e][h]) ----------------
__global__ void prep_wkt(const float* __restrict__ wk, unsigned short* __restrict__ wkt) {
    int idx = blockIdx.x * 256 + threadIdx.x;
    int h = idx >> 9, e = idx & 511;
    wkt[idx] = f2bf(wk[e * H_ + h]);
}

// ---------------- prep: qb[b][h] = hidden[b]@Wq[:,h] + bq[h] + bk[h] ----------------
__global__ void prep_qb(const float* __restrict__ hidden, const float* __restrict__ wq,
                        const float* __restrict__ bq, const float* __restrict__ bk,
                        float* __restrict__ qb) {
    __shared__ float hid[H_];
    int b = blockIdx.x, t = threadIdx.x;           // 256 threads
    hid[t]       = hidden[b * H_ + t];
    hid[t + 256] = hidden[b * H_ + t + 256];
    __syncthreads();
    for (int hh = t; hh < H_; hh += 256) {
        float s = 0.f;
        for (int e = 0; e < H_; ++e) s += hid[e] * wq[e * H_ + hh];
        qb[b * H_ + hh] = s + bq[hh] + bk[hh];
    }
}

// ---------------- main: partial scores over one 128-col n-chunk ----------------
// EXACT r5 structure (356 us best) with ONE change: prefetch depth 2 -> 3.
// grid 8192: xcd-chunked -> (b, s-tile 128, n-tile 128). block 256 thr = 4 waves (2M x 2N).
// A (enc f32) -> regs -> cvt bf16 -> ds_write b128 (2-buf ping-pong, XOR layout).
// B (Wkt bf16) -> global_load_lds DMA (4-buf ring, XOR layout, source-permuted).
// Runtime kc loop, counted vmcnt(12) steady-state, raw s_barrier (one per kc).
__global__ __launch_bounds__(256, 3) void scores_kernel(
    const float* __restrict__ enc, const unsigned short* __restrict__ wkt,
    const float* __restrict__ qb, const float* __restrict__ wv,
    float* __restrict__ part)
{
    __shared__ char lds[49152];   // A0@0, A1@8K, B0@16K, B1@24K, B2@32K, B3@40K

    int id = blockIdx.x;
    int xcd = id & 7, qq = id >> 3;
    int logical = xcd * 1024 + qq;
    int b  = logical >> 7;
    int r  = logical & 127;
    int st = r >> 2, nt = r & 3;
    int s0 = st * 128;

    const int tid  = threadIdx.x;
    const int lane = tid & 63;
    const int wave = tid >> 6;
    const int wr   = wave >> 1;      // M half (0,1)
    const int wc   = wave & 1;       // N half (0,1)
    const int l31  = lane & 31;
    const int g    = lane >> 5;

    const float* encb = enc + ((size_t)b * S_ + s0) * E_;

    // ---- A: thread t handles slotids 2t,2t+1; slotid -> row=sid>>2 (0..127), ksl=sid&3 (k=ksl*8) ----
    auto loadA = [&](int kc, float4 (&rg)[4]) {
#pragma unroll
        for (int j = 0; j < 2; ++j) {
            int sid = tid * 2 + j;
            int row = sid >> 2, ksl = sid & 3;
            const float* p = encb + (size_t)row * 512 + kc * 32 + ksl * 8;
            rg[j * 2 + 0] = *(const float4*)p;
            rg[j * 2 + 1] = *(const float4*)(p + 4);
        }
    };
    auto writeA = [&](char* buf, const float4 (&rg)[4]) {
#pragma unroll
        for (int j = 0; j < 2; ++j) {
            int sid = tid * 2 + j;
            int row = sid >> 2, ksl = sid & 3;
            int srow = row & 31;
            int sst  = ((row >> 5) * 4 + ksl) ^ (srow & 15);
            union { short8 s; unsigned u[4]; } u;
            u.u[0] = pk2(rg[j * 2].x, rg[j * 2].y);
            u.u[1] = pk2(rg[j * 2].z, rg[j * 2].w);
            u.u[2] = pk2(rg[j * 2 + 1].x, rg[j * 2 + 1].y);
            u.u[3] = pk2(rg[j * 2 + 1].z, rg[j * 2 + 1].w);
            *(short8*)(buf + srow * 256 + sst * 16) = u.s;
        }
    };
    // ---- B: 128 n x 32 k bf16 = 8KB DMA; stored [sn 32][16]: sl = ss^(sn&15); n=(sl>>2)*32+sn; k=(sl&3)*8
    auto stageB = [&](int kc, char* buf) {
#pragma unroll
        for (int p = 0; p < 2; ++p) {
            int gi0 = p * 256 + wave * 64;
            char* db = buf + gi0 * 16;                 // wave-uniform dest
            int gi = gi0 + lane;
            int sn = gi >> 4, ss = gi & 15;
            int sl = ss ^ (sn & 15);
            int n  = (sl >> 2) * 32 + sn;
            const unsigned short* gp = wkt + (size_t)(nt * 128 + n) * 512 + kc * 32 + (sl & 3) * 8;
            gload_lds16(gp, db);
        }
    };

    f32x16 acc[2][2];
#pragma unroll
    for (int mr = 0; mr < 2; ++mr)
#pragma unroll
        for (int nf = 0; nf < 2; ++nf)
#pragma unroll
            for (int e = 0; e < 16; ++e) acc[mr][nf][e] = 0.f;

    float4 ra[4], rb[4], rc[4];

    // prologue: 3 stages in flight, each stage FIFO = [B(2), A(4)] -> 18 vm ops
    stageB(0, lds + 16384);              loadA(0, ra);
    stageB(1, lds + 16384 + 8192);       loadA(1, rb);
    stageB(2, lds + 16384 + 16384);      loadA(2, rc);

    auto iter = [&](int kc, float4 (&rg)[4]) {
        if (kc <= 13) { VMCNT12; } else if (kc == 14) { VMCNT6; } else { VMCNT0; }
        char* Ab = lds + (kc & 1) * 8192;
        writeA(Ab, rg);                                  // publish A(kc)
        LGKM0;
        __builtin_amdgcn_s_barrier();
        __builtin_amdgcn_sched_barrier(0);
        if (kc < 13) {                                   // issue stage kc+3: [B, A]
            stageB(kc + 3, lds + 16384 + ((kc + 3) & 3) * 8192);
            loadA(kc + 3, rg);
        }
        const char* Bb = lds + 16384 + (kc & 3) * 8192;
#pragma unroll
        for (int ks = 0; ks < 2; ++ks) {
            short8 af[2], bf[2];
#pragma unroll
            for (int mr = 0; mr < 2; ++mr) {
                int sl = (wr * 2 + mr) * 4 + ks * 2 + g;
                af[mr] = *(const short8*)(Ab + l31 * 256 + ((sl ^ (l31 & 15)) << 4));
            }
#pragma unroll
            for (int nf = 0; nf < 2; ++nf) {
                int sl = (wc * 2 + nf) * 4 + ks * 2 + g;
                bf[nf] = *(const short8*)(Bb + l31 * 256 + ((sl ^ (l31 & 15)) << 4));
            }
            acc[0][0] = __builtin_amdgcn_mfma_f32_32x32x16_bf16(af[0], bf[0], acc[0][0], 0, 0, 0);
            acc[0][1] = __builtin_amdgcn_mfma_f32_32x32x16_bf16(af[0], bf[1], acc[0][1], 0, 0, 0);
            acc[1][0] = __builtin_amdgcn_mfma_f32_32x32x16_bf16(af[1], bf[0], acc[1][0], 0, 0, 0);
            acc[1][1] = __builtin_amdgcn_mfma_f32_32x32x16_bf16(af[1], bf[1], acc[1][1], 0, 0, 0);
        }
    };

    for (int t3 = 0; t3 < 5; ++t3) {
        iter(t3 * 3,     ra);
        iter(t3 * 3 + 1, rb);
        iter(t3 * 3 + 2, rc);
    }
    iter(15, ra);

    // ---- epilogue: p = sum_nf Wv[col]*tanh(qb[col]+acc) ----
    float p[2][16];
#pragma unroll
    for (int nf = 0; nf < 2; ++nf) {
        int col = nt * 128 + wc * 64 + nf * 32 + l31;
        float qv  = qb[b * H_ + col];
        float wvv = wv[col];
#pragma unroll
        for (int mr = 0; mr < 2; ++mr)
#pragma unroll
            for (int e = 0; e < 16; ++e) {
                float x  = qv + acc[mr][nf][e];
                float ex = __expf(2.f * x);
                float th = 1.f - 2.f / (ex + 1.f);
                float v  = wvv * th;
                p[mr][e] = nf ? (p[mr][e] + v) : v;
            }
    }

    __syncthreads();                                  // all GEMM LDS traffic done before reuse
    // ---- reduce over 32 lanes via LDS transpose (stride 36 floats; r3-verified) ----
    float* ps = (float*)lds;                          // [wave][64 rows][36]
#pragma unroll
    for (int mr = 0; mr < 2; ++mr)
#pragma unroll
        for (int e = 0; e < 16; ++e) {
            int row = mr * 32 + (e & 3) + 8 * (e >> 2) + 4 * g;
            ps[(wave * 64 + row) * 36 + l31] = p[mr][e];
        }
    __syncthreads();
    float rsum = 0.f;
    {
        const float* myrow = ps + (size_t)(wave * 64 + lane) * 36;
#pragma unroll
        for (int j = 0; j < 8; ++j) {
            float4 v = *(const float4*)(myrow + j * 4);
            rsum += (v.x + v.y) + (v.z + v.w);
        }
    }
    float* pf = (float*)(lds + 37888);                // 256 floats
    pf[wave * 64 + lane] = rsum;
    __syncthreads();
    if (tid < 128) {
        int wr2 = tid >> 6, rr = tid & 63;
        float v = pf[(wr2 * 2 + 0) * 64 + rr] + pf[(wr2 * 2 + 1) * 64 + rr];
        int s = s0 + wr2 * 64 + rr;
        part[((size_t)b * S_ + s) * 4 + nt] = v;
    }
}

// ---------------- masked softmax over S per batch row (sums 4 partials) ----------------
__global__ void softmax_kernel(const float* __restrict__ part, const int* __restrict__ mask,
                               const float* __restrict__ bvp, float* __restrict__ attn) {
    __shared__ float red[8];
    int b = blockIdx.x, tid = threadIdx.x;         // 512 threads, 8 waves
    int wid = tid >> 6, lane = tid & 63;
    float bv0 = bvp[0];
    float vals[8];
    float mx = -3.4e38f;
#pragma unroll
    for (int i = 0; i < 8; ++i) {
        int s = i * 512 + tid;
        float4 v = *(const float4*)(part + ((size_t)b * S_ + s) * 4);
        float sc = (v.x + v.y) + (v.z + v.w) + bv0;
        sc = mask[(size_t)b * S_ + s] ? sc : NEG_INF_;
        vals[i] = sc;
        mx = fmaxf(mx, sc);
    }
#pragma unroll
    for (int off = 1; off < 64; off <<= 1) mx = fmaxf(mx, __shfl_xor(mx, off));
    if (lane == 0) red[wid] = mx;
    __syncthreads();
    mx = red[0];
#pragma unroll
    for (int w = 1; w < 8; ++w) mx = fmaxf(mx, red[w]);
    __syncthreads();
    float sum = 0.f;
#pragma unroll
    for (int i = 0; i < 8; ++i) { vals[i] = __expf(vals[i] - mx); sum += vals[i]; }
#pragma unroll
    for (int off = 1; off < 64; off <<= 1) sum += __shfl_xor(sum, off);
    if (lane == 0) red[wid] = sum;
    __syncthreads();
    sum = red[0] + red[1] + red[2] + red[3] + red[4] + red[5] + red[6] + red[7];
    float inv = 1.f / sum;
#pragma unroll
    for (int i = 0; i < 8; ++i) attn[(size_t)b * S_ + i * 512 + tid] = vals[i] * inv;
}

// ---------------- context partial sums: part[c][b][e] ----------------
__global__ void ctx_partial(const float* __restrict__ attn, const float* __restrict__ enc,
                            float* __restrict__ part) {
    __shared__ float a[256];
    int c = blockIdx.x, b = blockIdx.y, t = threadIdx.x;   // 256 threads
    a[t] = attn[(size_t)b * S_ + c * 256 + t];
    __syncthreads();
    const float* ep = enc + (size_t)b * S_ * E_ + (size_t)c * 256 * E_ + t * 2;
    float x = 0.f, y = 0.f;
#pragma unroll 4
    for (int s = 0; s < 256; ++s) {
        float2 v = *(const float2*)(ep + (size_t)s * E_);
        x += a[s] * v.x;
        y += a[s] * v.y;
    }
    float* o = part + ((size_t)c * B_ + b) * E_ + t * 2;
    o[0] = x; o[1] = y;
}

__global__ void ctx_reduce(const float* __restrict__ part, float* __restrict__ ctx) {
    int idx = blockIdx.x * 256 + threadIdx.x;       // 0..32767
    float s = 0.f;
#pragma unroll
    for (int c = 0; c < 16; ++c) s += part[(size_t)c * (B_ * E_) + idx];
    ctx[idx] = s;
}

extern "C" void kernel_launch(void* const* d_in, const int* in_sizes, int n_in,
                              void* d_out, int out_size, void* d_ws, size_t ws_size,
                              hipStream_t stream) {
    const float* hidden = (const float*)d_in[0];
    const float* enc    = (const float*)d_in[1];
    const int*   mask   = (const int*)d_in[2];
    const float* Wq     = (const float*)d_in[3];
    const float* bq     = (const float*)d_in[4];
    const float* Wk     = (const float*)d_in[5];
    const float* bk     = (const float*)d_in[6];
    const float* Wv     = (const float*)d_in[7];
    const float* bv     = (const float*)d_in[8];

    float* out  = (float*)d_out;               // [B*E context][B*S attn]
    char*  ws   = (char*)d_ws;
    float*          qbuf   = (float*)ws;                         // 131072 B
    unsigned short* wkt    = (unsigned short*)(ws + 131072);     // 524288 B
    float*          pscore = (float*)(ws + 655360);              // 4 MB [b][s][4]
    float*          cpart  = (float*)(ws + 655360);              // aliases pscore (after softmax)

    float* ctx  = out;
    float* attn = out + B_ * E_;

    prep_wkt<<<1024, 256, 0, stream>>>(Wk, wkt);
    prep_qb<<<64, 256, 0, stream>>>(hidden, Wq, bq, bk, qbuf);
    scores_kernel<<<8192, 256, 0, stream>>>(enc, wkt, qbuf, Wv, pscore);
    softmax_kernel<<<64, 512, 0, stream>>>(pscore, mask, bv, attn);
    ctx_partial<<<dim3(16, 64), 256, 0, stream>>>(attn, enc, cpart);
    ctx_reduce<<<128, 256, 0, stream>>>(cpart, ctx);
}